// Round 1
// baseline (4596.983 us; speedup 1.0000x reference)
//
#include <hip/hip_runtime.h>
#include <math.h>

#define L1V 32760
#define CDIM 1536
#define TT 21
#define WW 52
#define HWD 1560
#define NH 12

__device__ __forceinline__ float wave_sum(float v) {
  v += __shfl_xor(v, 32);
  v += __shfl_xor(v, 16);
  v += __shfl_xor(v, 8);
  v += __shfl_xor(v, 4);
  v += __shfl_xor(v, 2);
  v += __shfl_xor(v, 1);
  return v;
}

// heat = sigmoid((layernorm(x) * (1+mod1+te) + mod0+te) . Wh + bh), one block per row
__global__ __launch_bounds__(256) void heat_kernel(
    const float* __restrict__ qh, const float* __restrict__ te,
    const float* __restrict__ mod, const float* __restrict__ Wh,
    const float* __restrict__ bh, float* __restrict__ heat) {
  __shared__ float red[8];
  const int l = blockIdx.x;
  const int tid = threadIdx.x;
  const float2* x2 = (const float2*)(qh + (size_t)l * CDIM);
  const float2* t2 = (const float2*)(te + (size_t)l * CDIM);
  float2 xv[3], tv[3];
  float sum = 0.f, sumsq = 0.f;
#pragma unroll
  for (int i = 0; i < 3; i++) {
    xv[i] = x2[tid + 256 * i];
    tv[i] = t2[tid + 256 * i];
    sum += xv[i].x + xv[i].y;
    sumsq += xv[i].x * xv[i].x + xv[i].y * xv[i].y;
  }
  float s1 = wave_sum(sum), s2 = wave_sum(sumsq);
  const int w = tid >> 6;
  if ((tid & 63) == 0) { red[w] = s1; red[4 + w] = s2; }
  __syncthreads();
  const float mu = (red[0] + red[1] + red[2] + red[3]) * (1.f / CDIM);
  const float ex2 = (red[4] + red[5] + red[6] + red[7]) * (1.f / CDIM);
  const float rs = rsqrtf(ex2 - mu * mu + 1e-6f);
  float dot = 0.f;
#pragma unroll
  for (int i = 0; i < 3; i++) {
    const int p = tid + 256 * i;
    float2 m0 = ((const float2*)mod)[p];
    float2 m1 = ((const float2*)mod)[768 + p];
    float2 wh = ((const float2*)Wh)[p];
    float xn;
    xn = (xv[i].x - mu) * rs;
    dot += (xn * (1.f + m1.x + tv[i].x) + m0.x + tv[i].x) * wh.x;
    xn = (xv[i].y - mu) * rs;
    dot += (xn * (1.f + m1.y + tv[i].y) + m0.y + tv[i].y) * wh.y;
  }
  float d1 = wave_sum(dot);
  __syncthreads();
  if ((tid & 63) == 0) red[w] = d1;
  __syncthreads();
  if (tid == 0) {
    float z = red[0] + red[1] + red[2] + red[3] + bh[0];
    heat[l] = 1.f / (1.f + expf(-z));
  }
}

// closed-form audio window gather: kvw[m] = kv[idx(t,j)], m = t*16+j
__global__ __launch_bounds__(256) void gather_kv(const float* __restrict__ kv,
                                                 float* __restrict__ kvw) {
  const int m = blockIdx.x;
  const int t = m >> 4, j = m & 15;
  int src = (t == 0) ? max(j - 11, 0) : min(max(8 * t - 10 + j, 0), 161);
  const float4* s = (const float4*)(kv + (size_t)src * CDIM);
  float4* d = (float4*)(kvw + (size_t)m * CDIM);
  for (int i = threadIdx.x; i < CDIM / 4; i += 256) d[i] = s[i];
}

// C[M,1536] = A[M,1536] @ W[1536,1536]^T + bias ; fp32, 128x128x16 tiles, 8x8 per thread
__global__ __launch_bounds__(256) void sgemm_nt(const float* __restrict__ A,
    const float* __restrict__ W, const float* __restrict__ bias,
    float* __restrict__ C, int M) {
  __shared__ float As[16][128];
  __shared__ float Bs[16][128];
  const int tid = threadIdx.x;
  const int n0 = blockIdx.x * 128;
  const int m0 = blockIdx.y * 128;
  const int lr = tid >> 2;             // 0..63
  const int lc = (tid & 3) << 2;       // 0,4,8,12
  const int ar0 = min(m0 + lr, M - 1);
  const int ar1 = min(m0 + lr + 64, M - 1);
  const float* a0 = A + (size_t)ar0 * CDIM + lc;
  const float* a1 = A + (size_t)ar1 * CDIM + lc;
  const float* b0 = W + (size_t)(n0 + lr) * CDIM + lc;
  const float* b1 = W + (size_t)(n0 + lr + 64) * CDIM + lc;
  const int tx = tid & 15;
  const int ty = tid >> 4;
  float acc[8][8];
#pragma unroll
  for (int i = 0; i < 8; i++)
#pragma unroll
    for (int j = 0; j < 8; j++) acc[i][j] = 0.f;

  for (int k0 = 0; k0 < CDIM; k0 += 16) {
    float4 av0 = *(const float4*)(a0 + k0);
    float4 av1 = *(const float4*)(a1 + k0);
    float4 bv0 = *(const float4*)(b0 + k0);
    float4 bv1 = *(const float4*)(b1 + k0);
    __syncthreads();
    As[lc + 0][lr] = av0.x; As[lc + 1][lr] = av0.y;
    As[lc + 2][lr] = av0.z; As[lc + 3][lr] = av0.w;
    As[lc + 0][lr + 64] = av1.x; As[lc + 1][lr + 64] = av1.y;
    As[lc + 2][lr + 64] = av1.z; As[lc + 3][lr + 64] = av1.w;
    Bs[lc + 0][lr] = bv0.x; Bs[lc + 1][lr] = bv0.y;
    Bs[lc + 2][lr] = bv0.z; Bs[lc + 3][lr] = bv0.w;
    Bs[lc + 0][lr + 64] = bv1.x; Bs[lc + 1][lr + 64] = bv1.y;
    Bs[lc + 2][lr + 64] = bv1.z; Bs[lc + 3][lr + 64] = bv1.w;
    __syncthreads();
#pragma unroll
    for (int kk = 0; kk < 16; kk++) {
      float4 a4 = *(const float4*)&As[kk][ty * 8];
      float4 a5 = *(const float4*)&As[kk][ty * 8 + 4];
      float4 b4 = *(const float4*)&Bs[kk][tx * 8];
      float4 b5 = *(const float4*)&Bs[kk][tx * 8 + 4];
      float ar[8] = {a4.x, a4.y, a4.z, a4.w, a5.x, a5.y, a5.z, a5.w};
      float br[8] = {b4.x, b4.y, b4.z, b4.w, b5.x, b5.y, b5.z, b5.w};
#pragma unroll
      for (int i = 0; i < 8; i++)
#pragma unroll
        for (int j = 0; j < 8; j++) acc[i][j] += ar[i] * br[j];
    }
  }
  const int cn = n0 + tx * 8;
  float4 bia = *(const float4*)&bias[cn];
  float4 bib = *(const float4*)&bias[cn + 4];
#pragma unroll
  for (int i = 0; i < 8; i++) {
    const int row = m0 + ty * 8 + i;
    if (row < M) {
      float4 r0 = {acc[i][0] + bia.x, acc[i][1] + bia.y,
                   acc[i][2] + bia.z, acc[i][3] + bia.w};
      float4 r1 = {acc[i][4] + bib.x, acc[i][5] + bib.y,
                   acc[i][6] + bib.z, acc[i][7] + bib.w};
      *(float4*)&C[(size_t)row * CDIM + cn] = r0;
      *(float4*)&C[(size_t)row * CDIM + cn + 4] = r1;
    }
  }
}

// RMS-norm over full C, apply g, then RoPE for Q (pairs 0..21 identity, 22..42 by h, 43..63 by w)
__global__ __launch_bounds__(256) void rmsrope_q(float* __restrict__ q,
    const float* __restrict__ g, const float* __restrict__ fr) {
  __shared__ float red[4];
  const int l = blockIdx.x;
  const int tid = threadIdx.x;
  float2* row = (float2*)(q + (size_t)l * CDIM);
  const int r = l % HWD;
  const int h = r / WW, w = r % WW;
  float2 xv[3];
  float ss = 0.f;
#pragma unroll
  for (int i = 0; i < 3; i++) {
    xv[i] = row[tid + 256 * i];
    ss += xv[i].x * xv[i].x + xv[i].y * xv[i].y;
  }
  float s1 = wave_sum(ss);
  if ((tid & 63) == 0) red[tid >> 6] = s1;
  __syncthreads();
  const float rs =
      rsqrtf((red[0] + red[1] + red[2] + red[3]) * (1.f / CDIM) + 1e-6f);
#pragma unroll
  for (int i = 0; i < 3; i++) {
    const int p = tid + 256 * i;
    const int pl = p & 63;
    float frc = 1.f, fis = 0.f;
    if (pl >= 22) {
      const int pos = (pl < 43) ? h : w;
      float2 f = ((const float2*)fr)[pos * 64 + pl];
      frc = f.x; fis = f.y;
    }
    float2 gv = ((const float2*)g)[p];
    float y0 = xv[i].x * rs * gv.x;
    float y1 = xv[i].y * rs * gv.y;
    row[p] = make_float2(y0 * frc - y1 * fis, y0 * fis + y1 * frc);
  }
}

// RMS-norm + RoPE for K (pairs 0..21 by s=row%16, rest identity)
__global__ __launch_bounds__(256) void rmsrope_k(float* __restrict__ k,
    const float* __restrict__ g, const float* __restrict__ fr) {
  __shared__ float red[4];
  const int l = blockIdx.x;
  const int tid = threadIdx.x;
  float2* row = (float2*)(k + (size_t)l * CDIM);
  const int s = l & 15;
  float2 xv[3];
  float ss = 0.f;
#pragma unroll
  for (int i = 0; i < 3; i++) {
    xv[i] = row[tid + 256 * i];
    ss += xv[i].x * xv[i].x + xv[i].y * xv[i].y;
  }
  float s1 = wave_sum(ss);
  if ((tid & 63) == 0) red[tid >> 6] = s1;
  __syncthreads();
  const float rs =
      rsqrtf((red[0] + red[1] + red[2] + red[3]) * (1.f / CDIM) + 1e-6f);
#pragma unroll
  for (int i = 0; i < 3; i++) {
    const int p = tid + 256 * i;
    const int pl = p & 63;
    float frc = 1.f, fis = 0.f;
    if (pl < 22) {
      float2 f = ((const float2*)fr)[s * 64 + pl];
      frc = f.x; fis = f.y;
    }
    float2 gv = ((const float2*)g)[p];
    float y0 = xv[i].x * rs * gv.x;
    float y1 = xv[i].y * rs * gv.y;
    row[p] = make_float2(y0 * frc - y1 * fis, y0 * fis + y1 * frc);
  }
}

// attention: one block per (frame, head, 16-row chunk); S=16 KV in LDS;
// in-place q->o (each lane reads only its own d-slice before writing it); heat folded in.
__global__ __launch_bounds__(256) void attn(float* __restrict__ qo,
    const float* __restrict__ kbuf, const float* __restrict__ vbuf,
    const float* __restrict__ heat) {
  __shared__ float ks[16][132];
  __shared__ float vs[16][132];
  const int t = blockIdx.z, n = blockIdx.y, ch = blockIdx.x;
  const int tid = threadIdx.x;
  {
    int s = tid >> 5;               // 0..7
    const int d4 = (tid & 31) * 4;  // 0..124
#pragma unroll
    for (int rep = 0; rep < 2; rep++, s += 8) {
      const size_t base = ((size_t)(t * 16 + s)) * CDIM + n * 128 + d4;
      *(float4*)&ks[s][d4] = *(const float4*)&kbuf[base];
      *(float4*)&vs[s][d4] = *(const float4*)&vbuf[base];
    }
  }
  __syncthreads();
  const int rl = ch * 16 + (tid >> 4);
  const int tx = tid & 15;
  if (rl < HWD) {
    const size_t gr = (size_t)(t * HWD + rl);
    float* qrow = qo + gr * CDIM + n * 128;
    float4 qa = *(const float4*)&qrow[tx * 4];
    float4 qb = *(const float4*)&qrow[64 + tx * 4];
    float sc[16];
#pragma unroll
    for (int s = 0; s < 16; s++) {
      float4 ka = *(const float4*)&ks[s][tx * 4];
      float4 kb = *(const float4*)&ks[s][64 + tx * 4];
      float p = qa.x * ka.x + qa.y * ka.y + qa.z * ka.z + qa.w * ka.w +
                qb.x * kb.x + qb.y * kb.y + qb.z * kb.z + qb.w * kb.w;
      p += __shfl_xor(p, 8, 16);
      p += __shfl_xor(p, 4, 16);
      p += __shfl_xor(p, 2, 16);
      p += __shfl_xor(p, 1, 16);
      sc[s] = p * 0.08838834764831845f;  // 1/sqrt(128)
    }
    float m = sc[0];
#pragma unroll
    for (int s = 1; s < 16; s++) m = fmaxf(m, sc[s]);
    float sum = 0.f;
#pragma unroll
    for (int s = 0; s < 16; s++) { sc[s] = expf(sc[s] - m); sum += sc[s]; }
    const float hv = heat[gr] / sum;
    float4 oa = {0, 0, 0, 0}, ob = {0, 0, 0, 0};
#pragma unroll
    for (int s = 0; s < 16; s++) {
      const float p = sc[s];
      float4 va = *(const float4*)&vs[s][tx * 4];
      float4 vb = *(const float4*)&vs[s][64 + tx * 4];
      oa.x += p * va.x; oa.y += p * va.y; oa.z += p * va.z; oa.w += p * va.w;
      ob.x += p * vb.x; ob.y += p * vb.y; ob.z += p * vb.z; ob.w += p * vb.w;
    }
    oa.x *= hv; oa.y *= hv; oa.z *= hv; oa.w *= hv;
    ob.x *= hv; ob.y *= hv; ob.z *= hv; ob.w *= hv;
    *(float4*)&qrow[tx * 4] = oa;
    *(float4*)&qrow[64 + tx * 4] = ob;
  }
}

extern "C" void kernel_launch(void* const* d_in, const int* in_sizes, int n_in,
                              void* d_out, int out_size, void* d_ws, size_t ws_size,
                              hipStream_t stream) {
  (void)in_sizes; (void)n_in; (void)out_size; (void)ws_size;
  const float* qh  = (const float*)d_in[0];
  const float* kvh = (const float*)d_in[1];
  const float* te  = (const float*)d_in[2];
  const float* qf  = (const float*)d_in[4];
  const float* kf  = (const float*)d_in[5];
  const float* Wq  = (const float*)d_in[6];
  const float* bq  = (const float*)d_in[7];
  const float* Wk  = (const float*)d_in[8];
  const float* bk  = (const float*)d_in[9];
  const float* Wv  = (const float*)d_in[10];
  const float* bv  = (const float*)d_in[11];
  const float* Wo  = (const float*)d_in[12];
  const float* bo  = (const float*)d_in[13];
  const float* gq  = (const float*)d_in[14];
  const float* gk  = (const float*)d_in[15];
  const float* mod = (const float*)d_in[16];
  const float* Wh  = (const float*)d_in[17];
  const float* bh  = (const float*)d_in[18];

  float* ws = (float*)d_ws;
  float* qbuf = ws;                               // 32760*1536
  float* heat = qbuf + (size_t)L1V * CDIM;        // 32760 (rounded to 32768)
  float* kvw  = heat + 32768;                     // 336*1536
  float* kbuf = kvw + 336 * CDIM;                 // 336*1536
  float* vbuf = kbuf + 336 * CDIM;                // 336*1536

  heat_kernel<<<L1V, 256, 0, stream>>>(qh, te, mod, Wh, bh, heat);
  gather_kv<<<336, 256, 0, stream>>>(kvh, kvw);
  sgemm_nt<<<dim3(12, 3), 256, 0, stream>>>(kvw, Wk, bk, kbuf, 336);
  sgemm_nt<<<dim3(12, 3), 256, 0, stream>>>(kvw, Wv, bv, vbuf, 336);
  sgemm_nt<<<dim3(12, 256), 256, 0, stream>>>(qh, Wq, bq, qbuf, L1V);
  rmsrope_k<<<336, 256, 0, stream>>>(kbuf, gk, kf);
  rmsrope_q<<<L1V, 256, 0, stream>>>(qbuf, gq, qf);
  attn<<<dim3(98, NH, TT), 256, 0, stream>>>(qbuf, kbuf, vbuf, heat);
  sgemm_nt<<<dim3(12, 256), 256, 0, stream>>>(qbuf, Wo, bo, (float*)d_out, L1V);
}

// Round 2
// 1656.299 us; speedup vs baseline: 2.7755x; 2.7755x over previous
//
#include <hip/hip_runtime.h>
#include <math.h>

#define L1V 32760
#define CDIM 1536
#define TT 21
#define WW 52
#define HWD 1560
#define NH 12

typedef unsigned short u16;
typedef __bf16 bf16x8 __attribute__((ext_vector_type(8)));
typedef float f32x4 __attribute__((ext_vector_type(4)));
typedef __attribute__((address_space(1))) const unsigned int as1_cu32;
typedef __attribute__((address_space(3))) unsigned int as3_u32;

__device__ __forceinline__ void async16(const void* g, void* l) {
  __builtin_amdgcn_global_load_lds((as1_cu32*)g, (as3_u32*)l, 16, 0, 0);
}

__device__ __forceinline__ u16 f2bf(float f) {
  unsigned u = __float_as_uint(f);
  unsigned r = u + 0x7fffu + ((u >> 16) & 1u);
  return (u16)(r >> 16);
}

__device__ __forceinline__ float wave_sum(float v) {
  v += __shfl_xor(v, 32);
  v += __shfl_xor(v, 16);
  v += __shfl_xor(v, 8);
  v += __shfl_xor(v, 4);
  v += __shfl_xor(v, 2);
  v += __shfl_xor(v, 1);
  return v;
}

// fp32 -> bf16 (RNE), 8 elems/thread
__global__ __launch_bounds__(256) void conv_bf16(const float* __restrict__ in,
                                                 u16* __restrict__ out, int n8) {
  int i = blockIdx.x * 256 + threadIdx.x;
  if (i < n8) {
    float4 a = ((const float4*)in)[2 * i];
    float4 b = ((const float4*)in)[2 * i + 1];
    ushort4 ua = make_ushort4(f2bf(a.x), f2bf(a.y), f2bf(a.z), f2bf(a.w));
    ushort4 ub = make_ushort4(f2bf(b.x), f2bf(b.y), f2bf(b.z), f2bf(b.w));
    ((ushort4*)out)[2 * i] = ua;
    ((ushort4*)out)[2 * i + 1] = ub;
  }
}

// heat = sigmoid((layernorm(x) * (1+mod1+te) + mod0+te) . Wh + bh), one block per row
__global__ __launch_bounds__(256) void heat_kernel(
    const float* __restrict__ qh, const float* __restrict__ te,
    const float* __restrict__ mod, const float* __restrict__ Wh,
    const float* __restrict__ bh, float* __restrict__ heat) {
  __shared__ float red[8];
  const int l = blockIdx.x;
  const int tid = threadIdx.x;
  const float2* x2 = (const float2*)(qh + (size_t)l * CDIM);
  const float2* t2 = (const float2*)(te + (size_t)l * CDIM);
  float2 xv[3], tv[3];
  float sum = 0.f, sumsq = 0.f;
#pragma unroll
  for (int i = 0; i < 3; i++) {
    xv[i] = x2[tid + 256 * i];
    tv[i] = t2[tid + 256 * i];
    sum += xv[i].x + xv[i].y;
    sumsq += xv[i].x * xv[i].x + xv[i].y * xv[i].y;
  }
  float s1 = wave_sum(sum), s2 = wave_sum(sumsq);
  const int w = tid >> 6;
  if ((tid & 63) == 0) { red[w] = s1; red[4 + w] = s2; }
  __syncthreads();
  const float mu = (red[0] + red[1] + red[2] + red[3]) * (1.f / CDIM);
  const float ex2 = (red[4] + red[5] + red[6] + red[7]) * (1.f / CDIM);
  const float rs = rsqrtf(ex2 - mu * mu + 1e-6f);
  float dot = 0.f;
#pragma unroll
  for (int i = 0; i < 3; i++) {
    const int p = tid + 256 * i;
    float2 m0 = ((const float2*)mod)[p];
    float2 m1 = ((const float2*)mod)[768 + p];
    float2 wh = ((const float2*)Wh)[p];
    float xn;
    xn = (xv[i].x - mu) * rs;
    dot += (xn * (1.f + m1.x + tv[i].x) + m0.x + tv[i].x) * wh.x;
    xn = (xv[i].y - mu) * rs;
    dot += (xn * (1.f + m1.y + tv[i].y) + m0.y + tv[i].y) * wh.y;
  }
  float d1 = wave_sum(dot);
  __syncthreads();
  if ((tid & 63) == 0) red[w] = d1;
  __syncthreads();
  if (tid == 0) {
    float z = red[0] + red[1] + red[2] + red[3] + bh[0];
    heat[l] = 1.f / (1.f + expf(-z));
  }
}

// closed-form audio window gather
__global__ __launch_bounds__(256) void gather_kv(const float* __restrict__ kv,
                                                 float* __restrict__ kvw) {
  const int m = blockIdx.x;
  const int t = m >> 4, j = m & 15;
  int src = (t == 0) ? max(j - 11, 0) : min(max(8 * t - 10 + j, 0), 161);
  const float4* s = (const float4*)(kv + (size_t)src * CDIM);
  float4* d = (float4*)(kvw + (size_t)m * CDIM);
  for (int i = threadIdx.x; i < CDIM / 4; i += 256) d[i] = s[i];
}

// fp32 GEMM kept for the tiny K/V projections (M=336)
__global__ __launch_bounds__(256) void sgemm_nt(const float* __restrict__ A,
    const float* __restrict__ W, const float* __restrict__ bias,
    float* __restrict__ C, int M) {
  __shared__ float As[16][128];
  __shared__ float Bs[16][128];
  const int tid = threadIdx.x;
  const int n0 = blockIdx.x * 128;
  const int m0 = blockIdx.y * 128;
  const int lr = tid >> 2;
  const int lc = (tid & 3) << 2;
  const int ar0 = min(m0 + lr, M - 1);
  const int ar1 = min(m0 + lr + 64, M - 1);
  const float* a0 = A + (size_t)ar0 * CDIM + lc;
  const float* a1 = A + (size_t)ar1 * CDIM + lc;
  const float* b0 = W + (size_t)(n0 + lr) * CDIM + lc;
  const float* b1 = W + (size_t)(n0 + lr + 64) * CDIM + lc;
  const int tx = tid & 15;
  const int ty = tid >> 4;
  float acc[8][8];
#pragma unroll
  for (int i = 0; i < 8; i++)
#pragma unroll
    for (int j = 0; j < 8; j++) acc[i][j] = 0.f;

  for (int k0 = 0; k0 < CDIM; k0 += 16) {
    float4 av0 = *(const float4*)(a0 + k0);
    float4 av1 = *(const float4*)(a1 + k0);
    float4 bv0 = *(const float4*)(b0 + k0);
    float4 bv1 = *(const float4*)(b1 + k0);
    __syncthreads();
    As[lc + 0][lr] = av0.x; As[lc + 1][lr] = av0.y;
    As[lc + 2][lr] = av0.z; As[lc + 3][lr] = av0.w;
    As[lc + 0][lr + 64] = av1.x; As[lc + 1][lr + 64] = av1.y;
    As[lc + 2][lr + 64] = av1.z; As[lc + 3][lr + 64] = av1.w;
    Bs[lc + 0][lr] = bv0.x; Bs[lc + 1][lr] = bv0.y;
    Bs[lc + 2][lr] = bv0.z; Bs[lc + 3][lr] = bv0.w;
    Bs[lc + 0][lr + 64] = bv1.x; Bs[lc + 1][lr + 64] = bv1.y;
    Bs[lc + 2][lr + 64] = bv1.z; Bs[lc + 3][lr + 64] = bv1.w;
    __syncthreads();
#pragma unroll
    for (int kk = 0; kk < 16; kk++) {
      float4 a4 = *(const float4*)&As[kk][ty * 8];
      float4 a5 = *(const float4*)&As[kk][ty * 8 + 4];
      float4 b4 = *(const float4*)&Bs[kk][tx * 8];
      float4 b5 = *(const float4*)&Bs[kk][tx * 8 + 4];
      float ar[8] = {a4.x, a4.y, a4.z, a4.w, a5.x, a5.y, a5.z, a5.w};
      float br[8] = {b4.x, b4.y, b4.z, b4.w, b5.x, b5.y, b5.z, b5.w};
#pragma unroll
      for (int i = 0; i < 8; i++)
#pragma unroll
        for (int j = 0; j < 8; j++) acc[i][j] += ar[i] * br[j];
    }
  }
  const int cn = n0 + tx * 8;
  float4 bia = *(const float4*)&bias[cn];
  float4 bib = *(const float4*)&bias[cn + 4];
#pragma unroll
  for (int i = 0; i < 8; i++) {
    const int row = m0 + ty * 8 + i;
    if (row < M) {
      float4 r0 = {acc[i][0] + bia.x, acc[i][1] + bia.y,
                   acc[i][2] + bia.z, acc[i][3] + bia.w};
      float4 r1 = {acc[i][4] + bib.x, acc[i][5] + bib.y,
                   acc[i][6] + bib.z, acc[i][7] + bib.w};
      *(float4*)&C[(size_t)row * CDIM + cn] = r0;
      *(float4*)&C[(size_t)row * CDIM + cn + 4] = r1;
    }
  }
}

// bf16 MFMA GEMM: C[M,1536] = A[M,1536](bf16) @ W[1536,1536]^T(bf16) + bias, fp32 out.
// 128x128 tile, BK=32, mfma_f32_16x16x32_bf16, global_load_lds width=16.
__global__ __launch_bounds__(256) void gemm_bf16(
    const u16* __restrict__ A, const u16* __restrict__ W,
    const float* __restrict__ bias, float* __restrict__ C, int M) {
  __shared__ __align__(16) u16 As[128 * 32];
  __shared__ __align__(16) u16 Bs[128 * 32];
  const int tid = threadIdx.x;
  const int n0 = blockIdx.x * 128;
  const int m0 = blockIdx.y * 128;
  // staging: chunk c covers row c>>2, k-bytes (c&3)*16; lane chunks are wave-contiguous
  const int r0 = tid >> 2;
  const int kc = (tid & 3) * 8;
  const int am0 = min(m0 + r0, M - 1);
  const int am1 = min(m0 + 64 + r0, M - 1);
  const u16* ga0 = A + (size_t)am0 * CDIM + kc;
  const u16* ga1 = A + (size_t)am1 * CDIM + kc;
  const u16* gb0 = W + (size_t)(n0 + r0) * CDIM + kc;
  const u16* gb1 = W + (size_t)(n0 + 64 + r0) * CDIM + kc;
  u16* lA0 = As + (tid & 0xC0) * 8;   // wave-uniform LDS base
  u16* lA1 = lA0 + 2048;
  u16* lB0 = Bs + (tid & 0xC0) * 8;
  u16* lB1 = lB0 + 2048;

  const int lane = tid & 63;
  const int l15 = lane & 15;
  const int quad = lane >> 4;
  const int wid = tid >> 6;
  const int wm = wid >> 1;
  const int wn = wid & 1;

  f32x4 acc[4][4];
  const f32x4 z = {0.f, 0.f, 0.f, 0.f};
#pragma unroll
  for (int i = 0; i < 4; i++)
#pragma unroll
    for (int j = 0; j < 4; j++) acc[i][j] = z;

  for (int k0 = 0; k0 < CDIM; k0 += 32) {
    __syncthreads();  // prior iter's LDS reads done
    async16(ga0 + k0, lA0);
    async16(ga1 + k0, lA1);
    async16(gb0 + k0, lB0);
    async16(gb1 + k0, lB1);
    __syncthreads();  // drains vmcnt -> tiles resident
    bf16x8 af[4], bfr[4];
#pragma unroll
    for (int mi = 0; mi < 4; mi++)
      af[mi] = *(const bf16x8*)&As[(wm * 64 + mi * 16 + l15) * 32 + quad * 8];
#pragma unroll
    for (int ni = 0; ni < 4; ni++)
      bfr[ni] = *(const bf16x8*)&Bs[(wn * 64 + ni * 16 + l15) * 32 + quad * 8];
#pragma unroll
    for (int mi = 0; mi < 4; mi++)
#pragma unroll
      for (int ni = 0; ni < 4; ni++)
        acc[mi][ni] = __builtin_amdgcn_mfma_f32_16x16x32_bf16(
            af[mi], bfr[ni], acc[mi][ni], 0, 0, 0);
  }
#pragma unroll
  for (int ni = 0; ni < 4; ni++) {
    const int col = n0 + wn * 64 + ni * 16 + l15;
    const float bv = bias[col];
#pragma unroll
    for (int mi = 0; mi < 4; mi++) {
      const int rbase = m0 + wm * 64 + mi * 16 + quad * 4;
#pragma unroll
      for (int r = 0; r < 4; r++) {
        const int row = rbase + r;
        if (row < M) C[(size_t)row * CDIM + col] = acc[mi][ni][r] + bv;
      }
    }
  }
}

// RMS-norm over full C, apply g, then RoPE for Q
__global__ __launch_bounds__(256) void rmsrope_q(float* __restrict__ q,
    const float* __restrict__ g, const float* __restrict__ fr) {
  __shared__ float red[4];
  const int l = blockIdx.x;
  const int tid = threadIdx.x;
  float2* row = (float2*)(q + (size_t)l * CDIM);
  const int r = l % HWD;
  const int h = r / WW, w = r % WW;
  float2 xv[3];
  float ss = 0.f;
#pragma unroll
  for (int i = 0; i < 3; i++) {
    xv[i] = row[tid + 256 * i];
    ss += xv[i].x * xv[i].x + xv[i].y * xv[i].y;
  }
  float s1 = wave_sum(ss);
  if ((tid & 63) == 0) red[tid >> 6] = s1;
  __syncthreads();
  const float rs =
      rsqrtf((red[0] + red[1] + red[2] + red[3]) * (1.f / CDIM) + 1e-6f);
#pragma unroll
  for (int i = 0; i < 3; i++) {
    const int p = tid + 256 * i;
    const int pl = p & 63;
    float frc = 1.f, fis = 0.f;
    if (pl >= 22) {
      const int pos = (pl < 43) ? h : w;
      float2 f = ((const float2*)fr)[pos * 64 + pl];
      frc = f.x; fis = f.y;
    }
    float2 gv = ((const float2*)g)[p];
    float y0 = xv[i].x * rs * gv.x;
    float y1 = xv[i].y * rs * gv.y;
    row[p] = make_float2(y0 * frc - y1 * fis, y0 * fis + y1 * frc);
  }
}

// RMS-norm + RoPE for K
__global__ __launch_bounds__(256) void rmsrope_k(float* __restrict__ k,
    const float* __restrict__ g, const float* __restrict__ fr) {
  __shared__ float red[4];
  const int l = blockIdx.x;
  const int tid = threadIdx.x;
  float2* row = (float2*)(k + (size_t)l * CDIM);
  const int s = l & 15;
  float2 xv[3];
  float ss = 0.f;
#pragma unroll
  for (int i = 0; i < 3; i++) {
    xv[i] = row[tid + 256 * i];
    ss += xv[i].x * xv[i].x + xv[i].y * xv[i].y;
  }
  float s1 = wave_sum(ss);
  if ((tid & 63) == 0) red[tid >> 6] = s1;
  __syncthreads();
  const float rs =
      rsqrtf((red[0] + red[1] + red[2] + red[3]) * (1.f / CDIM) + 1e-6f);
#pragma unroll
  for (int i = 0; i < 3; i++) {
    const int p = tid + 256 * i;
    const int pl = p & 63;
    float frc = 1.f, fis = 0.f;
    if (pl < 22) {
      float2 f = ((const float2*)fr)[s * 64 + pl];
      frc = f.x; fis = f.y;
    }
    float2 gv = ((const float2*)g)[p];
    float y0 = xv[i].x * rs * gv.x;
    float y1 = xv[i].y * rs * gv.y;
    row[p] = make_float2(y0 * frc - y1 * fis, y0 * fis + y1 * frc);
  }
}

// attention: S=16 KV in LDS; heat folded in; writes bf16 output for Wo GEMM
__global__ __launch_bounds__(256) void attn(const float* __restrict__ q,
    const float* __restrict__ kbuf, const float* __restrict__ vbuf,
    const float* __restrict__ heat, u16* __restrict__ obuf) {
  __shared__ float ks[16][132];
  __shared__ float vs[16][132];
  const int t = blockIdx.z, n = blockIdx.y, ch = blockIdx.x;
  const int tid = threadIdx.x;
  {
    int s = tid >> 5;
    const int d4 = (tid & 31) * 4;
#pragma unroll
    for (int rep = 0; rep < 2; rep++, s += 8) {
      const size_t base = ((size_t)(t * 16 + s)) * CDIM + n * 128 + d4;
      *(float4*)&ks[s][d4] = *(const float4*)&kbuf[base];
      *(float4*)&vs[s][d4] = *(const float4*)&vbuf[base];
    }
  }
  __syncthreads();
  const int rl = ch * 16 + (tid >> 4);
  const int tx = tid & 15;
  if (rl < HWD) {
    const size_t gr = (size_t)(t * HWD + rl);
    const float* qrow = q + gr * CDIM + n * 128;
    float4 qa = *(const float4*)&qrow[tx * 4];
    float4 qb = *(const float4*)&qrow[64 + tx * 4];
    float sc[16];
#pragma unroll
    for (int s = 0; s < 16; s++) {
      float4 ka = *(const float4*)&ks[s][tx * 4];
      float4 kb = *(const float4*)&ks[s][64 + tx * 4];
      float p = qa.x * ka.x + qa.y * ka.y + qa.z * ka.z + qa.w * ka.w +
                qb.x * kb.x + qb.y * kb.y + qb.z * kb.z + qb.w * kb.w;
      p += __shfl_xor(p, 8, 16);
      p += __shfl_xor(p, 4, 16);
      p += __shfl_xor(p, 2, 16);
      p += __shfl_xor(p, 1, 16);
      sc[s] = p * 0.08838834764831845f;
    }
    float m = sc[0];
#pragma unroll
    for (int s = 1; s < 16; s++) m = fmaxf(m, sc[s]);
    float sum = 0.f;
#pragma unroll
    for (int s = 0; s < 16; s++) { sc[s] = expf(sc[s] - m); sum += sc[s]; }
    const float hv = heat[gr] / sum;
    float4 oa = {0, 0, 0, 0}, ob = {0, 0, 0, 0};
#pragma unroll
    for (int s = 0; s < 16; s++) {
      const float p = sc[s];
      float4 va = *(const float4*)&vs[s][tx * 4];
      float4 vb = *(const float4*)&vs[s][64 + tx * 4];
      oa.x += p * va.x; oa.y += p * va.y; oa.z += p * va.z; oa.w += p * va.w;
      ob.x += p * vb.x; ob.y += p * vb.y; ob.z += p * vb.z; ob.w += p * vb.w;
    }
    u16* orow = obuf + gr * CDIM + n * 128;
    ushort4 pa = make_ushort4(f2bf(oa.x * hv), f2bf(oa.y * hv),
                              f2bf(oa.z * hv), f2bf(oa.w * hv));
    ushort4 pb = make_ushort4(f2bf(ob.x * hv), f2bf(ob.y * hv),
                              f2bf(ob.z * hv), f2bf(ob.w * hv));
    *(ushort4*)&orow[tx * 4] = pa;
    *(ushort4*)&orow[64 + tx * 4] = pb;
  }
}

extern "C" void kernel_launch(void* const* d_in, const int* in_sizes, int n_in,
                              void* d_out, int out_size, void* d_ws, size_t ws_size,
                              hipStream_t stream) {
  (void)in_sizes; (void)n_in; (void)out_size; (void)ws_size;
  const float* qh  = (const float*)d_in[0];
  const float* kvh = (const float*)d_in[1];
  const float* te  = (const float*)d_in[2];
  const float* qf  = (const float*)d_in[4];
  const float* kf  = (const float*)d_in[5];
  const float* Wq  = (const float*)d_in[6];
  const float* bq  = (const float*)d_in[7];
  const float* Wk  = (const float*)d_in[8];
  const float* bk  = (const float*)d_in[9];
  const float* Wv  = (const float*)d_in[10];
  const float* bv  = (const float*)d_in[11];
  const float* Wo  = (const float*)d_in[12];
  const float* bo  = (const float*)d_in[13];
  const float* gq  = (const float*)d_in[14];
  const float* gk  = (const float*)d_in[15];
  const float* mod = (const float*)d_in[16];
  const float* Wh  = (const float*)d_in[17];
  const float* bh  = (const float*)d_in[18];

  float* ws = (float*)d_ws;
  float* qbuf = ws;                               // 50,319,360 f (fp32 q)
  float* heat = qbuf + (size_t)L1V * CDIM;        // 32768 f
  float* kvw  = heat + 32768;                     // 516096 f
  float* kbuf = kvw + 516096;                     // 516096 f
  float* vbuf = kbuf + 516096;                    // 516096 f
  u16* Abf  = (u16*)(vbuf + 516096);              // 50,319,360 u16 (qh bf16; reused as obuf)
  u16* Wqb  = (u16*)((float*)(vbuf + 516096) + 25159680);  // 2,359,296 u16
  u16* Wob  = Wqb + 2359296;                      // 2,359,296 u16
  u16* obuf = Abf;  // qh-bf16 dead after Wq GEMM; attn output reuses it

  conv_bf16<<<(6289920 + 255) / 256, 256, 0, stream>>>(qh, Abf, 6289920);
  conv_bf16<<<(294912 + 255) / 256, 256, 0, stream>>>(Wq, Wqb, 294912);
  conv_bf16<<<(294912 + 255) / 256, 256, 0, stream>>>(Wo, Wob, 294912);
  heat_kernel<<<L1V, 256, 0, stream>>>(qh, te, mod, Wh, bh, heat);
  gather_kv<<<336, 256, 0, stream>>>(kvh, kvw);
  sgemm_nt<<<dim3(12, 3), 256, 0, stream>>>(kvw, Wk, bk, kbuf, 336);
  sgemm_nt<<<dim3(12, 3), 256, 0, stream>>>(kvw, Wv, bv, vbuf, 336);
  gemm_bf16<<<dim3(12, 256), 256, 0, stream>>>(Abf, Wqb, bq, qbuf, L1V);
  rmsrope_k<<<336, 256, 0, stream>>>(kbuf, gk, kf);
  rmsrope_q<<<L1V, 256, 0, stream>>>(qbuf, gq, qf);
  attn<<<dim3(98, NH, TT), 256, 0, stream>>>(qbuf, kbuf, vbuf, heat, obuf);
  gemm_bf16<<<dim3(12, 256), 256, 0, stream>>>(obuf, Wob, bo, (float*)d_out, L1V);
}